// Round 1
// baseline (63.356 us; speedup 1.0000x reference)
//
#include <hip/hip_runtime.h>
#include <hip/hip_bf16.h>

#define NROWS 8192
#define DDIM 128
#define EPSV 1e-8f

typedef __attribute__((ext_vector_type(8))) short bf16x8;
typedef __attribute__((ext_vector_type(4))) float f32x4;

// ---------------------------------------------------------------------------
// prep: fp32 -> bf16 (RNE) copies of both inputs + fp32 row norms.
// One wave (64 lanes) per row; each lane handles 2 elements (float2).
// ---------------------------------------------------------------------------
__global__ __launch_bounds__(256) void prep_kernel(
    const float* __restrict__ in1, const float* __restrict__ in2,
    __hip_bfloat16* __restrict__ Ab, __hip_bfloat16* __restrict__ Bb,
    float* __restrict__ n1, float* __restrict__ n2) {
  int gw = (blockIdx.x * 256 + threadIdx.x) >> 6;   // global wave id = row id
  int l = threadIdx.x & 63;
  const float* src;
  __hip_bfloat16* dst;
  float* nrm;
  if (gw < NROWS) {
    src = in1 + (size_t)gw * DDIM;
    dst = Ab + (size_t)gw * DDIM;
    nrm = n1 + gw;
  } else {
    int r = gw - NROWS;
    src = in2 + (size_t)r * DDIM;
    dst = Bb + (size_t)r * DDIM;
    nrm = n2 + r;
  }
  float2 v = ((const float2*)src)[l];
  float s = v.x * v.x + v.y * v.y;
  __hip_bfloat162 h;
  h.x = __float2bfloat16(v.x);
  h.y = __float2bfloat16(v.y);
  ((__hip_bfloat162*)dst)[l] = h;
#pragma unroll
  for (int off = 1; off < 64; off <<= 1) s += __shfl_xor(s, off);
  if (l == 0) *nrm = sqrtf(s);
}

// ---------------------------------------------------------------------------
// cos_gemm: C[i][j] = dot(A_i, B_j) / max(n1[i]*n2[j], eps)
// 128x128 tile per block, full K=128 staged once (32KB + 32KB LDS).
// global_load_lds width=16 with inverse-swizzled global source addresses;
// ds_read_b128 with XOR swizzle (row&7)<<4 -> ~conflict-free.
// ---------------------------------------------------------------------------
__device__ inline void async_load16(const void* g, void* l) {
  __builtin_amdgcn_global_load_lds(
      (const __attribute__((address_space(1))) void*)g,
      (__attribute__((address_space(3))) void*)l, 16, 0, 0);
}

__global__ __launch_bounds__(256, 2) void cos_gemm(
    const __hip_bfloat16* __restrict__ Ab, const __hip_bfloat16* __restrict__ Bb,
    const float* __restrict__ n1, const float* __restrict__ n2,
    float* __restrict__ out) {
  __shared__ __hip_bfloat16 ldsA[128 * 128];  // 32 KB
  __shared__ __hip_bfloat16 ldsB[128 * 128];  // 32 KB

  const int tid = threadIdx.x;
  const int l = tid & 63;
  const int w = tid >> 6;       // wave 0..3
  const int q = l >> 4;         // 0..3
  const int c16 = l & 15;       // 0..15
  const int brow = blockIdx.x * 128;
  const int bcol = blockIdx.y * 128;

  const char* Ag = (const char*)Ab + (size_t)brow * 256;  // 256 B per row
  const char* Bg = (const char*)Bb + (size_t)bcol * 256;
  char* lA = (char*)ldsA;
  char* lB = (char*)ldsB;

  // Stage both 128x128-bf16 tiles. Each wave: 8 loads x 1KB per tile.
  // LDS dest is linear (wave-uniform base + lane*16); source address carries
  // the inverse swizzle so that LDS[row][b] = A[row][b ^ ((row&7)<<4)].
#pragma unroll
  for (int i = 0; i < 8; ++i) {
    int r0 = w * 32 + i * 4;          // wave-uniform row group (4 rows)
    int row = r0 + q;                 // this lane's row
    int boff = c16 * 16;              // byte offset within row
    int src = row * 256 + (boff ^ ((row & 7) << 4));
    async_load16(Ag + src, lA + r0 * 256);
    async_load16(Bg + src, lB + r0 * 256);
  }
  __syncthreads();

  const int wr = w >> 1, wc = w & 1;  // 2x2 wave grid, 64x64 out each
  f32x4 acc[4][4] = {};

#pragma unroll
  for (int s = 0; s < 4; ++s) {       // K steps of 32
    bf16x8 af[4], bfr[4];
    int kb = s * 64 + q * 16;         // byte offset of this lane's 8 bf16
#pragma unroll
    for (int m = 0; m < 4; ++m) {
      int rowa = wr * 64 + m * 16 + c16;
      af[m] = *(const bf16x8*)(lA + rowa * 256 + (kb ^ ((rowa & 7) << 4)));
      int rowb = wc * 64 + m * 16 + c16;
      bfr[m] = *(const bf16x8*)(lB + rowb * 256 + (kb ^ ((rowb & 7) << 4)));
    }
#pragma unroll
    for (int m = 0; m < 4; ++m)
#pragma unroll
      for (int n = 0; n < 4; ++n)
        acc[m][n] =
            __builtin_amdgcn_mfma_f32_16x16x32_bf16(af[m], bfr[n], acc[m][n], 0, 0, 0);
  }

  // Epilogue: C/D layout col = lane&15, row = (lane>>4)*4 + reg  [m89]
#pragma unroll
  for (int m = 0; m < 4; ++m) {
    int grow_base = brow + wr * 64 + m * 16 + q * 4;
#pragma unroll
    for (int r = 0; r < 4; ++r) {
      int grow = grow_base + r;
      float nn1 = n1[grow];
#pragma unroll
      for (int n = 0; n < 4; ++n) {
        int gcol = bcol + wc * 64 + n * 16 + c16;
        float denom = fmaxf(nn1 * n2[gcol], EPSV);
        out[(size_t)grow * NROWS + gcol] = __fdividef(acc[m][n][r], denom);
      }
    }
  }
}

extern "C" void kernel_launch(void* const* d_in, const int* in_sizes, int n_in,
                              void* d_out, int out_size, void* d_ws, size_t ws_size,
                              hipStream_t stream) {
  const float* in1 = (const float*)d_in[0];
  const float* in2 = (const float*)d_in[1];
  float* out = (float*)d_out;
  char* ws = (char*)d_ws;

  __hip_bfloat16* Ab = (__hip_bfloat16*)(ws);                          // 2 MB
  __hip_bfloat16* Bb = (__hip_bfloat16*)(ws + (size_t)NROWS * DDIM * 2);  // 2 MB
  float* n1 = (float*)(ws + (size_t)NROWS * DDIM * 4);                 // 32 KB
  float* n2 = (float*)(ws + (size_t)NROWS * DDIM * 4 + NROWS * 4);     // 32 KB

  // 16384 rows total (A + B), one wave per row, 4 waves per block
  prep_kernel<<<dim3(16384 / 4), 256, 0, stream>>>(in1, in2, Ab, Bb, n1, n2);
  cos_gemm<<<dim3(64, 64), 256, 0, stream>>>(Ab, Bb, n1, n2, out);
}